// Round 2
// baseline (233.282 us; speedup 1.0000x reference)
//
#include <hip/hip_runtime.h>
#include <math.h>

#define T_DIM  1024
#define B_DIM  8
#define IN_D   512
#define NROWS  (T_DIM * B_DIM)      // 8192
#define EPSF   1e-8f

#define CHUNK  32
#define NCHUNK (T_DIM / CHUNK)      // 32
#define SEG    64
#define NSEG   (T_DIM / SEG)        // 16

typedef float vfloat4 __attribute__((ext_vector_type(4)));  // nontemporal-store-compatible

// ---- workspace layout (floats) ----
#define OFF_WT   0                                  // 512*192      = 98304
#define OFF_V    (OFF_WT + IN_D * 192)              // + 524288
#define OFF_K    (OFF_V  + NROWS * 64)              // + 524288  (becomes w=k*decay in place)
#define OFF_Z    (OFF_K  + NROWS * 64)              // + 524288  (alpha logits -> log alpha in place)
#define OFF_SEG  (OFF_Z  + NROWS * 64)              // + 16*512 = 8192
#define OFF_TOT  (OFF_SEG + NSEG * B_DIM * 64)      // + 512
#define OFF_P    (OFF_TOT + B_DIM * 64)             // + 32*8*4096 = 1048576  (total ~10.9 MB)

// K0: concat+transpose weights -> Wt[i][c], i<512, c<192 (c: 0..63 Wv, 64..127 Wk, 128..191 Wa)
__global__ void k0_wt(const float* __restrict__ Wv, const float* __restrict__ Wk,
                      const float* __restrict__ Wa, float* __restrict__ Wt) {
    int idx = blockIdx.x * 256 + threadIdx.x;       // < 512*192 = 98304
    int i = idx / 192, c = idx % 192;
    float v;
    if (c < 64)       v = Wv[c * IN_D + i];
    else if (c < 128) v = Wk[(c - 64) * IN_D + i];
    else              v = Wa[(c - 128) * IN_D + i];
    Wt[i * 192 + c] = v;
}

// K1: projections. 256 blocks x 512 thr; block = 32 rows of x(8192,512) -> V,K,Z (row-major, 64 wide)
__global__ __launch_bounds__(512) void k1_proj(
        const float* __restrict__ x, const float* __restrict__ Wt,
        const float* __restrict__ bv, const float* __restrict__ bk, const float* __restrict__ ba,
        float* __restrict__ V, float* __restrict__ Kb, float* __restrict__ Zb) {
    __shared__ float xs[32 * 64];      // 8 KB  (x K-slice)
    __shared__ float wsm[64 * 192];    // 48 KB (Wt K-slice)
    const int tid = threadIdx.x;
    const int c  = tid & 63;           // output column within each of the 3 matrices
    const int rg = tid >> 6;           // 0..7
    const int row0 = blockIdx.x * 32;

    float acc[4][3];
#pragma unroll
    for (int j = 0; j < 4; ++j) { acc[j][0] = 0.f; acc[j][1] = 0.f; acc[j][2] = 0.f; }

    for (int ks = 0; ks < IN_D; ks += 64) {
        { // stage x slice: 512 float4, 1 per thread
            int r = tid >> 4, f = tid & 15;
            float4 v4 = reinterpret_cast<const float4*>(x)[((row0 + r) * IN_D + ks) / 4 + f];
            reinterpret_cast<float4*>(xs)[r * 16 + f] = v4;
        }
#pragma unroll
        for (int q = 0; q < 6; ++q) { // stage Wt slice: 3072 float4, 6 per thread
            int i = tid + q * 512;
            int kk = i / 48, f = i % 48;
            float4 v4 = reinterpret_cast<const float4*>(Wt)[((ks + kk) * 192) / 4 + f];
            reinterpret_cast<float4*>(wsm)[kk * 48 + f] = v4;
        }
        __syncthreads();

        for (int kk = 0; kk < 64; kk += 4) {
            float4 xv[4];
#pragma unroll
            for (int j = 0; j < 4; ++j)
                xv[j] = reinterpret_cast<const float4*>(xs)[((rg + 8 * j) * 64 + kk) >> 2];
#pragma unroll
            for (int q = 0; q < 4; ++q) {
                float w0 = wsm[(kk + q) * 192 + c];
                float w1 = wsm[(kk + q) * 192 + 64 + c];
                float w2 = wsm[(kk + q) * 192 + 128 + c];
#pragma unroll
                for (int j = 0; j < 4; ++j) {
                    float xx = (&xv[j].x)[q];
                    acc[j][0] = fmaf(xx, w0, acc[j][0]);
                    acc[j][1] = fmaf(xx, w1, acc[j][1]);
                    acc[j][2] = fmaf(xx, w2, acc[j][2]);
                }
            }
        }
        __syncthreads();
    }
    float bvc = bv[c], bkc = bk[c], bac = ba[c];
#pragma unroll
    for (int j = 0; j < 4; ++j) {
        int row = row0 + rg + 8 * j;
        V[row * 64 + c]  = acc[j][0] + bvc;
        Kb[row * 64 + c] = acc[j][1] + bkc;
        Zb[row * 64 + c] = acc[j][2] + bac;
    }
}

// K2a: per-segment log(sigmoid) + segment sums. 128 blocks (b,s) x 64 thr (lane=n). Z -> log alpha in place.
__global__ void k2a_logs(float* __restrict__ Z, float* __restrict__ seg) {
    int b = blockIdx.x & 7, s = blockIdx.x >> 3;
    int n = threadIdx.x;
    int base = b * 64 + n;
    float accv = 0.f;
    for (int i = 0; i < SEG; ++i) {
        int t = s * SEG + i;
        float z = Z[t * 512 + base];
        float a = 1.f / (1.f + expf(-z));
        float l = logf(fmaxf(a, EPSF));
        Z[t * 512 + base] = l;
        accv += l;
    }
    seg[s * 512 + base] = accv;
}

// K2b: scan segment sums -> exclusive prefix (in place) + totals. 1 block x 512 thr.
__global__ void k2b_scan(float* __restrict__ seg, float* __restrict__ tot) {
    int i = threadIdx.x;
    float run = 0.f;
#pragma unroll
    for (int s = 0; s < NSEG; ++s) {
        float v = seg[s * 512 + i];
        seg[s * 512 + i] = run;
        run += v;
    }
    tot[i] = run;
}

// K2c: w[t] = k[t] * exp(logcum[t]) / (exp(total)+eps), Kb in place. 128 blocks x 64 thr.
__global__ void k2c_w(const float* __restrict__ Z, const float* __restrict__ seg,
                      const float* __restrict__ tot, float* __restrict__ Kb) {
    int b = blockIdx.x & 7, s = blockIdx.x >> 3;
    int n = threadIdx.x;
    int base = b * 64 + n;
    float run = seg[s * 512 + base];
    float invden = 1.f / (expf(tot[base]) + EPSF);
    for (int i = 0; i < SEG; ++i) {
        int t = s * SEG + i;
        run += Z[t * 512 + base];
        float decay = expf(run) * invden;
        Kb[t * 512 + base] *= decay;
    }
}

// K3: per-chunk partial outer sums P[c][b][d][n]. 256 blocks (b,c) x 256 thr.
__global__ __launch_bounds__(256) void k3_partial(const float* __restrict__ V,
                                                  const float* __restrict__ W,
                                                  float* __restrict__ P) {
    __shared__ float vs[CHUNK * 64];
    __shared__ float wsh[CHUNK * 64];
    int b = blockIdx.x & 7, cch = blockIdx.x >> 3;
    int tid = threadIdx.x;
    int dg = tid >> 4, n4 = tid & 15;      // d = dg + 16q, n = 4*n4 + j
#pragma unroll
    for (int q = 0; q < 2; ++q) {
        int i = tid + q * 256;
        int il = i >> 4, f = i & 15;
        int row = (cch * CHUNK + il) * 8 + b;
        reinterpret_cast<float4*>(vs)[il * 16 + f]  = reinterpret_cast<const float4*>(V)[row * 16 + f];
        reinterpret_cast<float4*>(wsh)[il * 16 + f] = reinterpret_cast<const float4*>(W)[row * 16 + f];
    }
    __syncthreads();
    float4 acc[4];
#pragma unroll
    for (int q = 0; q < 4; ++q) acc[q] = make_float4(0.f, 0.f, 0.f, 0.f);

#pragma unroll 4
    for (int i = 0; i < CHUNK; ++i) {
        float4 wv = reinterpret_cast<const float4*>(wsh)[i * 16 + n4];
#pragma unroll
        for (int q = 0; q < 4; ++q) {
            float vd = vs[i * 64 + dg + 16 * q];
            acc[q].x = fmaf(vd, wv.x, acc[q].x);
            acc[q].y = fmaf(vd, wv.y, acc[q].y);
            acc[q].z = fmaf(vd, wv.z, acc[q].z);
            acc[q].w = fmaf(vd, wv.w, acc[q].w);
        }
    }
    float* Pp = P + (cch * 8 + b) * 4096;
#pragma unroll
    for (int q = 0; q < 4; ++q)
        *reinterpret_cast<float4*>(Pp + (dg + 16 * q) * 64 + 4 * n4) = acc[q];
}

// K4: exclusive prefix over chunks, in place. 128 blocks x 256 thr.
__global__ void k4_prefix(float* __restrict__ P) {
    int gid = blockIdx.x * 256 + threadIdx.x;   // < 32768
    int b = gid >> 12, dn = gid & 4095;
    float vals[NCHUNK];
#pragma unroll
    for (int c = 0; c < NCHUNK; ++c) vals[c] = P[(c * 8 + b) * 4096 + dn];
    float run = 0.f;
#pragma unroll
    for (int c = 0; c < NCHUNK; ++c) { P[(c * 8 + b) * 4096 + dn] = run; run += vals[c]; }
}

// K5: main cumsum + store. 256 blocks (b,c) x 256 thr. Writes 134 MB (the roofline floor).
__global__ __launch_bounds__(256) void k5_main(const float* __restrict__ V,
                                               const float* __restrict__ W,
                                               const float* __restrict__ P,
                                               float* __restrict__ S) {
    __shared__ float vs[CHUNK * 64];
    __shared__ float wsh[CHUNK * 64];
    int b = blockIdx.x & 7, cch = blockIdx.x >> 3;
    int tid = threadIdx.x;
    int dg = tid >> 4, n4 = tid & 15;
#pragma unroll
    for (int q = 0; q < 2; ++q) {
        int i = tid + q * 256;
        int il = i >> 4, f = i & 15;
        int row = (cch * CHUNK + il) * 8 + b;
        reinterpret_cast<float4*>(vs)[il * 16 + f]  = reinterpret_cast<const float4*>(V)[row * 16 + f];
        reinterpret_cast<float4*>(wsh)[il * 16 + f] = reinterpret_cast<const float4*>(W)[row * 16 + f];
    }
    vfloat4 acc[4];
    const float* Pp = P + (cch * 8 + b) * 4096;
#pragma unroll
    for (int q = 0; q < 4; ++q)
        acc[q] = *reinterpret_cast<const vfloat4*>(Pp + (dg + 16 * q) * 64 + 4 * n4);
    __syncthreads();

#pragma unroll 4
    for (int i = 0; i < CHUNK; ++i) {
        float4 wv = reinterpret_cast<const float4*>(wsh)[i * 16 + n4];
        int t = cch * CHUNK + i;
        float* Sb = S + (size_t)t * 32768 + b * 4096;
#pragma unroll
        for (int q = 0; q < 4; ++q) {
            float vd = vs[i * 64 + dg + 16 * q];
            acc[q].x = fmaf(vd, wv.x, acc[q].x);
            acc[q].y = fmaf(vd, wv.y, acc[q].y);
            acc[q].z = fmaf(vd, wv.z, acc[q].z);
            acc[q].w = fmaf(vd, wv.w, acc[q].w);
            __builtin_nontemporal_store(acc[q],
                reinterpret_cast<vfloat4*>(Sb + (dg + 16 * q) * 64 + 4 * n4));
        }
    }
}

extern "C" void kernel_launch(void* const* d_in, const int* in_sizes, int n_in,
                              void* d_out, int out_size, void* d_ws, size_t ws_size,
                              hipStream_t stream) {
    const float* x  = (const float*)d_in[0];
    const float* Wv = (const float*)d_in[1];
    const float* bv = (const float*)d_in[2];
    const float* Wk = (const float*)d_in[3];
    const float* bk = (const float*)d_in[4];
    const float* Wa = (const float*)d_in[5];
    const float* ba = (const float*)d_in[6];
    float* S  = (float*)d_out;
    float* ws = (float*)d_ws;

    float* Wt  = ws + OFF_WT;
    float* V   = ws + OFF_V;
    float* Kb  = ws + OFF_K;
    float* Zb  = ws + OFF_Z;
    float* seg = ws + OFF_SEG;
    float* tot = ws + OFF_TOT;
    float* P   = ws + OFF_P;

    k0_wt     <<<384, 256, 0, stream>>>(Wv, Wk, Wa, Wt);
    k1_proj   <<<256, 512, 0, stream>>>(x, Wt, bv, bk, ba, V, Kb, Zb);
    k2a_logs  <<<128,  64, 0, stream>>>(Zb, seg);
    k2b_scan  <<<  1, 512, 0, stream>>>(seg, tot);
    k2c_w     <<<128,  64, 0, stream>>>(Zb, seg, tot, Kb);
    k3_partial<<<256, 256, 0, stream>>>(V, Kb, P);
    k4_prefix <<<128, 256, 0, stream>>>(P);
    k5_main   <<<256, 256, 0, stream>>>(V, Kb, P, S);
}

// Round 3
// 212.713 us; speedup vs baseline: 1.0967x; 1.0967x over previous
//
#include <hip/hip_runtime.h>
#include <math.h>

#define T_DIM  1024
#define B_DIM  8
#define IN_D   512
#define NROWS  (T_DIM * B_DIM)      // 8192
#define EPSF   1e-8f

#define CHUNK  16
#define NCHUNK (T_DIM / CHUNK)      // 64
#define SEG    16
#define NSEG   (T_DIM / SEG)        // 64

typedef float vfloat4 __attribute__((ext_vector_type(4)));

// ---- workspace layout (floats) ----
#define OFF_WT   0                                  // 512*192      = 98304
#define OFF_V    (OFF_WT + IN_D * 192)
#define OFF_K    (OFF_V  + NROWS * 64)              // becomes w=k*decay in place
#define OFF_Z    (OFF_K  + NROWS * 64)              // alpha logits -> log alpha in place
#define OFF_SEG  (OFF_Z  + NROWS * 64)              // 64*512
#define OFF_TOT  (OFF_SEG + NSEG * B_DIM * 64)      // 512
#define OFF_P    (OFF_TOT + B_DIM * 64)             // 64*8*4096 = 2097152

// K0: concat+transpose weights -> Wt[i][c], i<512, c<192
__global__ void k0_wt(const float* __restrict__ Wv, const float* __restrict__ Wk,
                      const float* __restrict__ Wa, float* __restrict__ Wt) {
    int idx = blockIdx.x * 256 + threadIdx.x;       // < 98304
    int i = idx / 192, c = idx % 192;
    float v;
    if (c < 64)       v = Wv[c * IN_D + i];
    else if (c < 128) v = Wk[(c - 64) * IN_D + i];
    else              v = Wa[(c - 128) * IN_D + i];
    Wt[i * 192 + c] = v;
}

// K1: projections, all-b128 LDS. 256 blocks x 256 thr; block = 32 rows, K-split-2.
// Thread (within K-half): rq=0..7 (4 rows), cq=0..15 (1 col-quad per matrix). 48 FMA / 4 b128 per kk.
__global__ __launch_bounds__(256) void k1_proj(
        const float* __restrict__ x, const float* __restrict__ Wt,
        const float* __restrict__ bv, const float* __restrict__ bk, const float* __restrict__ ba,
        float* __restrict__ V, float* __restrict__ Kb, float* __restrict__ Zb) {
    __shared__ float xs[2][32][32];     // [half][kk][row] 8 KB, transposed x
    __shared__ float wsm[2][32][192];   // [half][kk][col] 48 KB
    const int tid  = threadIdx.x;
    const int h    = tid >> 7;          // K half: 0 -> K[0:256), 1 -> K[256:512)
    const int t7   = tid & 127;
    const int rq   = t7 >> 4;           // row quad 0..7
    const int cq   = t7 & 15;           // col quad 0..15
    const int row0 = blockIdx.x * 32;

    float4 acc[4][3];
#pragma unroll
    for (int j = 0; j < 4; ++j)
#pragma unroll
        for (int m = 0; m < 3; ++m) acc[j][m] = make_float4(0.f, 0.f, 0.f, 0.f);

    for (int s = 0; s < 8; ++s) {       // K-slice of 32 per half
        // stage x transposed: 512 float4 loads -> scalar transpose writes (bank-clean)
#pragma unroll
        for (int q = 0; q < 2; ++q) {
            int idx = tid + q * 256;            // 0..511
            int hh = idx >> 8, r = idx & 31, f = (idx >> 5) & 7;
            float4 v4 = reinterpret_cast<const float4*>(x)[((row0 + r) * IN_D + hh * 256 + s * 32 + f * 4) >> 2];
            xs[hh][f * 4 + 0][r] = v4.x;
            xs[hh][f * 4 + 1][r] = v4.y;
            xs[hh][f * 4 + 2][r] = v4.z;
            xs[hh][f * 4 + 3][r] = v4.w;
        }
        // stage Wt slice: 3072 float4, direct b128 writes
#pragma unroll
        for (int q = 0; q < 12; ++q) {
            int idx = tid + q * 256;            // 0..3071
            int hh = idx / 1536;
            int rem = idx - hh * 1536;
            int kk = rem / 48;
            int f  = rem - kk * 48;
            float4 v4 = reinterpret_cast<const float4*>(Wt)[((hh * 256 + s * 32 + kk) * 192 + f * 4) >> 2];
            *reinterpret_cast<float4*>(&wsm[hh][kk][f * 4]) = v4;
        }
        __syncthreads();

#pragma unroll 4
        for (int kk = 0; kk < 32; ++kk) {
            float4 xv = *reinterpret_cast<const float4*>(&xs[h][kk][rq * 4]);
#pragma unroll
            for (int m = 0; m < 3; ++m) {
                float4 wq = *reinterpret_cast<const float4*>(&wsm[h][kk][m * 64 + cq * 4]);
#pragma unroll
                for (int j = 0; j < 4; ++j) {
                    float xx = (&xv.x)[j];
                    acc[j][m].x = fmaf(xx, wq.x, acc[j][m].x);
                    acc[j][m].y = fmaf(xx, wq.y, acc[j][m].y);
                    acc[j][m].z = fmaf(xx, wq.z, acc[j][m].z);
                    acc[j][m].w = fmaf(xx, wq.w, acc[j][m].w);
                }
            }
        }
        __syncthreads();
    }

    // cross-half reduce via LDS (reuse wsm; stride 52 floats to dodge bank conflicts)
    float* red = &wsm[0][0][0];
    if (h == 1) {
#pragma unroll
        for (int j = 0; j < 4; ++j)
#pragma unroll
            for (int m = 0; m < 3; ++m)
                *reinterpret_cast<float4*>(&red[t7 * 52 + (j * 3 + m) * 4]) = acc[j][m];
    }
    __syncthreads();
    if (h == 0) {
        float4 bv4 = *reinterpret_cast<const float4*>(&bv[cq * 4]);
        float4 bk4 = *reinterpret_cast<const float4*>(&bk[cq * 4]);
        float4 ba4 = *reinterpret_cast<const float4*>(&ba[cq * 4]);
#pragma unroll
        for (int j = 0; j < 4; ++j) {
            int row = row0 + rq * 4 + j;
#pragma unroll
            for (int m = 0; m < 3; ++m) {
                float4 o = *reinterpret_cast<const float4*>(&red[t7 * 52 + (j * 3 + m) * 4]);
                o.x += (&acc[j][m].x)[0]; // add own half
                o.x = acc[j][m].x + (&o.x)[0] - acc[j][m].x; // (kept simple below)
            }
            float4 o0 = *reinterpret_cast<const float4*>(&red[t7 * 52 + (j * 3 + 0) * 4]);
            float4 o1 = *reinterpret_cast<const float4*>(&red[t7 * 52 + (j * 3 + 1) * 4]);
            float4 o2 = *reinterpret_cast<const float4*>(&red[t7 * 52 + (j * 3 + 2) * 4]);
            float4 r0, r1, r2;
            r0.x = acc[j][0].x + o0.x + bv4.x; r0.y = acc[j][0].y + o0.y + bv4.y;
            r0.z = acc[j][0].z + o0.z + bv4.z; r0.w = acc[j][0].w + o0.w + bv4.w;
            r1.x = acc[j][1].x + o1.x + bk4.x; r1.y = acc[j][1].y + o1.y + bk4.y;
            r1.z = acc[j][1].z + o1.z + bk4.z; r1.w = acc[j][1].w + o1.w + bk4.w;
            r2.x = acc[j][2].x + o2.x + ba4.x; r2.y = acc[j][2].y + o2.y + ba4.y;
            r2.z = acc[j][2].z + o2.z + ba4.z; r2.w = acc[j][2].w + o2.w + ba4.w;
            *reinterpret_cast<float4*>(&V [row * 64 + cq * 4]) = r0;
            *reinterpret_cast<float4*>(&Kb[row * 64 + cq * 4]) = r1;
            *reinterpret_cast<float4*>(&Zb[row * 64 + cq * 4]) = r2;
        }
    }
}

// K2a: log(sigmoid) + segment sums. 512 blocks (b,s) x 64 thr. Z -> log alpha in place.
__global__ void k2a_logs(float* __restrict__ Z, float* __restrict__ seg) {
    int b = blockIdx.x & 7, s = blockIdx.x >> 3;
    int n = threadIdx.x;
    int base = b * 64 + n;
    float accv = 0.f;
#pragma unroll
    for (int i = 0; i < SEG; ++i) {
        int t = s * SEG + i;
        float z = Z[t * 512 + base];
        float a = 1.f / (1.f + expf(-z));
        float l = logf(fmaxf(a, EPSF));
        Z[t * 512 + base] = l;
        accv += l;
    }
    seg[s * 512 + base] = accv;
}

// K2b: exclusive scan of 64 segment sums per channel + totals. 1 block x 512 thr.
__global__ void k2b_scan(float* __restrict__ seg, float* __restrict__ tot) {
    int i = threadIdx.x;
    float vals[NSEG];
#pragma unroll
    for (int s = 0; s < NSEG; ++s) vals[s] = seg[s * 512 + i];
    float run = 0.f;
#pragma unroll
    for (int s = 0; s < NSEG; ++s) { seg[s * 512 + i] = run; run += vals[s]; }
    tot[i] = run;
}

// K2c: w[t] = k[t]*exp(logcum[t])/(exp(total)+eps). 512 blocks x 64 thr. Kb in place.
__global__ void k2c_w(const float* __restrict__ Z, const float* __restrict__ seg,
                      const float* __restrict__ tot, float* __restrict__ Kb) {
    int b = blockIdx.x & 7, s = blockIdx.x >> 3;
    int n = threadIdx.x;
    int base = b * 64 + n;
    float run = seg[s * 512 + base];
    float invden = 1.f / (expf(tot[base]) + EPSF);
#pragma unroll
    for (int i = 0; i < SEG; ++i) {
        int t = s * SEG + i;
        run += Z[t * 512 + base];
        Kb[t * 512 + base] *= expf(run) * invden;
    }
}

// K3: per-chunk partial outer sums P[c][b][d][n]. 512 blocks (b,c) x 256 thr.
__global__ __launch_bounds__(256) void k3_partial(const float* __restrict__ V,
                                                  const float* __restrict__ W,
                                                  float* __restrict__ P) {
    __shared__ float vs[CHUNK * 64];
    __shared__ float wsh[CHUNK * 64];
    int b = blockIdx.x & 7, cch = blockIdx.x >> 3;
    int tid = threadIdx.x;
    int dg = tid >> 4, n4 = tid & 15;
    {
        int il = tid >> 4, f = tid & 15;
        int row = (cch * CHUNK + il) * 8 + b;
        reinterpret_cast<float4*>(vs)[il * 16 + f]  = reinterpret_cast<const float4*>(V)[row * 16 + f];
        reinterpret_cast<float4*>(wsh)[il * 16 + f] = reinterpret_cast<const float4*>(W)[row * 16 + f];
    }
    __syncthreads();
    float4 acc[4];
#pragma unroll
    for (int q = 0; q < 4; ++q) acc[q] = make_float4(0.f, 0.f, 0.f, 0.f);

#pragma unroll
    for (int i = 0; i < CHUNK; ++i) {
        float4 wv = reinterpret_cast<const float4*>(wsh)[i * 16 + n4];
#pragma unroll
        for (int q = 0; q < 4; ++q) {
            float vd = vs[i * 64 + dg + 16 * q];
            acc[q].x = fmaf(vd, wv.x, acc[q].x);
            acc[q].y = fmaf(vd, wv.y, acc[q].y);
            acc[q].z = fmaf(vd, wv.z, acc[q].z);
            acc[q].w = fmaf(vd, wv.w, acc[q].w);
        }
    }
    float* Pp = P + (cch * 8 + b) * 4096;
#pragma unroll
    for (int q = 0; q < 4; ++q)
        *reinterpret_cast<float4*>(Pp + (dg + 16 * q) * 64 + 4 * n4) = acc[q];
}

// K4: exclusive prefix over 64 chunks, in place. 128 blocks x 256 thr.
__global__ __launch_bounds__(256) void k4_prefix(float* __restrict__ P) {
    int gid = blockIdx.x * 256 + threadIdx.x;   // < 32768
    int b = gid >> 12, dn = gid & 4095;
    float run = 0.f;
#pragma unroll
    for (int c = 0; c < NCHUNK; ++c) {
        float v = P[(c * 8 + b) * 4096 + dn];
        P[(c * 8 + b) * 4096 + dn] = run;
        run += v;
    }
}

// K5: main cumsum + streaming store (134 MB). 512 blocks (b,c) x 256 thr.
__global__ __launch_bounds__(256) void k5_main(const float* __restrict__ V,
                                               const float* __restrict__ W,
                                               const float* __restrict__ P,
                                               float* __restrict__ S) {
    __shared__ float vs[CHUNK * 64];
    __shared__ float wsh[CHUNK * 64];
    int b = blockIdx.x & 7, cch = blockIdx.x >> 3;
    int tid = threadIdx.x;
    int dg = tid >> 4, n4 = tid & 15;
    {
        int il = tid >> 4, f = tid & 15;
        int row = (cch * CHUNK + il) * 8 + b;
        reinterpret_cast<float4*>(vs)[il * 16 + f]  = reinterpret_cast<const float4*>(V)[row * 16 + f];
        reinterpret_cast<float4*>(wsh)[il * 16 + f] = reinterpret_cast<const float4*>(W)[row * 16 + f];
    }
    vfloat4 acc[4];
    const float* Pp = P + (cch * 8 + b) * 4096;
#pragma unroll
    for (int q = 0; q < 4; ++q)
        acc[q] = *reinterpret_cast<const vfloat4*>(Pp + (dg + 16 * q) * 64 + 4 * n4);
    __syncthreads();

#pragma unroll
    for (int i = 0; i < CHUNK; ++i) {
        float4 wv = reinterpret_cast<const float4*>(wsh)[i * 16 + n4];
        int t = cch * CHUNK + i;
        float* Sb = S + (size_t)t * 32768 + b * 4096;
#pragma unroll
        for (int q = 0; q < 4; ++q) {
            float vd = vs[i * 64 + dg + 16 * q];
            acc[q].x = fmaf(vd, wv.x, acc[q].x);
            acc[q].y = fmaf(vd, wv.y, acc[q].y);
            acc[q].z = fmaf(vd, wv.z, acc[q].z);
            acc[q].w = fmaf(vd, wv.w, acc[q].w);
            __builtin_nontemporal_store(acc[q],
                reinterpret_cast<vfloat4*>(Sb + (dg + 16 * q) * 64 + 4 * n4));
        }
    }
}

extern "C" void kernel_launch(void* const* d_in, const int* in_sizes, int n_in,
                              void* d_out, int out_size, void* d_ws, size_t ws_size,
                              hipStream_t stream) {
    const float* x  = (const float*)d_in[0];
    const float* Wv = (const float*)d_in[1];
    const float* bv = (const float*)d_in[2];
    const float* Wk = (const float*)d_in[3];
    const float* bk = (const float*)d_in[4];
    const float* Wa = (const float*)d_in[5];
    const float* ba = (const float*)d_in[6];
    float* S  = (float*)d_out;
    float* ws = (float*)d_ws;

    float* Wt  = ws + OFF_WT;
    float* V   = ws + OFF_V;
    float* Kb  = ws + OFF_K;
    float* Zb  = ws + OFF_Z;
    float* seg = ws + OFF_SEG;
    float* tot = ws + OFF_TOT;
    float* P   = ws + OFF_P;

    k0_wt     <<<384, 256, 0, stream>>>(Wv, Wk, Wa, Wt);
    k1_proj   <<<256, 256, 0, stream>>>(x, Wt, bv, bk, ba, V, Kb, Zb);
    k2a_logs  <<<512,  64, 0, stream>>>(Zb, seg);
    k2b_scan  <<<  1, 512, 0, stream>>>(seg, tot);
    k2c_w     <<<512,  64, 0, stream>>>(Zb, seg, tot, Kb);
    k3_partial<<<512, 256, 0, stream>>>(V, Kb, P);
    k4_prefix <<<128, 256, 0, stream>>>(P);
    k5_main   <<<512, 256, 0, stream>>>(V, Kb, P, S);
}